// Round 5
// baseline (137.947 us; speedup 1.0000x reference)
//
#include <hip/hip_runtime.h>
#include <math.h>

#define N_HITS 100000
#define P_PART 300
#define NSPLIT 20
#define PB (P_PART / NSPLIT)   // 15 centers per y-split
#define HPT 4                  // hits per thread
#define TILE (256 * HPT)       // 1024 hits per block-x
#define NBINS 16
#define Q_MIN 0.01f
#define R_THLD 10.0f
#define PT_THLD 0.9f

// ws layout (bytes):
//   [0,    2400): u64 best[300]                (zeroed)  -- packed (beta_bits<<32)|~i
//   [2400, 2404): u32 doneA                    (zeroed)
//   [2404, 2408): u32 doneB                    (zeroed)
//   [2408, 2412): u32 nmask                    (zeroed)
//   [2416, 2672): double bins[16][2]           (zeroed)
//   [2688, 12288): float4 c[600]: c[2p]=x_a[p], c[2p+1]=(|x_a|^2, q_a, 0, 0)

__global__ __launch_bounds__(256) void kA_scan(
        const float* __restrict__ beta,
        const float* __restrict__ x,
        const int* __restrict__ pid,
        const int* __restrict__ recon,
        const float* __restrict__ tp,
        unsigned long long* __restrict__ best,
        unsigned int* __restrict__ nmask,
        unsigned int* __restrict__ doneA,
        float4* __restrict__ c,
        int nblocks) {
    int i = blockIdx.x * 256 + threadIdx.x;
    if (i < N_HITS) {
        int p = pid[i];
        if (p > 0) {
            // q = atanh(b)^2 + c is monotonic in b on (0,1) -> argmax q == argmax beta.
            // beta > 0 -> float bits order like values. ~i => ties pick smallest i
            // (jnp.argmax first-occurrence semantics).
            unsigned long long pack =
                ((unsigned long long)__float_as_uint(beta[i]) << 32) |
                (unsigned long long)(~(unsigned int)i);
            atomicMax(&best[p - 1], pack);
        }
        if (recon[i] > 0 && tp[i] > PT_THLD) atomicAdd(nmask, 1u);
    }
    // last-finishing block gathers the condensation centers
    __shared__ int isLast;
    if (threadIdx.x == 0) {
        __threadfence();
        unsigned int old = atomicAdd(doneA, 1u);
        isLast = (old == (unsigned int)(nblocks - 1)) ? 1 : 0;
    }
    __syncthreads();
    if (isLast) {
        for (int p = threadIdx.x; p < P_PART; p += 256) {
            unsigned long long b = atomicOr(&best[p], 0ULL);  // coherent read
            unsigned int idx = (b == 0ULL) ? 0u : ~(unsigned int)(b & 0xffffffffULL);
            float a = atanhf(beta[idx]);
            float4 xa = reinterpret_cast<const float4*>(x)[idx];
            float na = xa.x * xa.x + xa.y * xa.y + xa.z * xa.z + xa.w * xa.w;
            c[2 * p] = xa;
            c[2 * p + 1] = make_float4(na, a * a + Q_MIN, 0.f, 0.f);
        }
    }
}

__global__ __launch_bounds__(256, 8) void kB_main(
        const float* __restrict__ beta,
        const float* __restrict__ x,
        const int* __restrict__ pid,
        const int* __restrict__ recon,
        const float* __restrict__ tp,
        const float4* __restrict__ c,
        const unsigned int* __restrict__ nmask,
        double* __restrict__ bins,
        unsigned int* __restrict__ doneB,
        float* __restrict__ out,
        int totalB) {
    __shared__ float4 xa_s[PB];
    __shared__ float2 nq_s[PB];     // (|x_a|^2, q_a)
    int p0 = blockIdx.y * PB;
    if (threadIdx.x < PB) {
        float4 r1 = c[2 * (p0 + threadIdx.x) + 1];
        xa_s[threadIdx.x] = c[2 * (p0 + threadIdx.x)];
        nq_s[threadIdx.x] = make_float2(r1.x, r1.y);
    }
    __syncthreads();

    int base = blockIdx.x * TILE + threadIdx.x;
    float4 m2[HPT];                 // -2 * x_i
    float  sx[HPT];                 // |x_i|^2 + 1e-8
    float  q[HPT], aq[HPT], racc[HPT];
    int    pm1[HPT];
    #pragma unroll
    for (int h = 0; h < HPT; ++h) {
        int i = base + h * 256;
        bool valid = (i < N_HITS);
        int ii = valid ? i : 0;
        float4 xi = reinterpret_cast<const float4*>(x)[ii];
        m2[h] = make_float4(-2.f * xi.x, -2.f * xi.y, -2.f * xi.z, -2.f * xi.w);
        sx[h] = xi.x * xi.x + xi.y * xi.y + xi.z * xi.z + xi.w * xi.w + 1e-8f;
        float a = atanhf(beta[ii]);
        q[h] = valid ? (a * a + Q_MIN) : 0.f;    // q=0 nullifies OOB lanes
        pm1[h] = valid ? (pid[ii] - 1) : -1;
        aq[h] = (valid && recon[ii] > 0 && tp[ii] > PT_THLD) ? q[h] : 0.f;
        racc[h] = 0.f;
    }

    #pragma unroll 5
    for (int p = 0; p < PB; ++p) {
        float4 xa = xa_s[p];        // uniform -> LDS broadcast, 0 conflicts
        float2 nq = nq_s[p];
        #pragma unroll
        for (int h = 0; h < HPT; ++h) {
            float n = sx[h] + nq.x;
            n = fmaf(m2[h].x, xa.x, n);
            n = fmaf(m2[h].y, xa.y, n);
            n = fmaf(m2[h].z, xa.z, n);
            n = fmaf(m2[h].w, xa.w, n);
            float s = __builtin_amdgcn_sqrtf(fmaxf(n, 0.f));   // raw v_sqrt_f32
            racc[h] = fmaf(fmaxf(R_THLD - s, 0.f), nq.y, racc[h]);
        }
    }

    float att = 0.f, rep = 0.f;
    #pragma unroll
    for (int h = 0; h < HPT; ++h) {
        int lp = pm1[h] - p0;
        if (lp >= 0 && lp < PB) {   // this split owns the own-pid term
            float4 xa = xa_s[lp];
            float2 nq = nq_s[lp];
            // IDENTICAL op sequence as the loop -> exact cancellation
            float n = sx[h] + nq.x;
            n = fmaf(m2[h].x, xa.x, n);
            n = fmaf(m2[h].y, xa.y, n);
            n = fmaf(m2[h].z, xa.z, n);
            n = fmaf(m2[h].w, xa.w, n);
            float s = __builtin_amdgcn_sqrtf(fmaxf(n, 0.f));
            racc[h] -= fmaxf(R_THLD - s, 0.f) * nq.y;
            att += aq[h] * (n - 1e-8f) * nq.y;   // attractive: nsq without eps
        }
        rep += q[h] * racc[h];
    }

    // wave-64 shuffle reduce, then block reduce
    #pragma unroll
    for (int off = 32; off > 0; off >>= 1) {
        att += __shfl_down(att, off, 64);
        rep += __shfl_down(rep, off, 64);
    }
    __shared__ float sA[4], sR[4];
    __shared__ int isLast;
    int wid = threadIdx.x >> 6;
    if ((threadIdx.x & 63) == 0) { sA[wid] = att; sR[wid] = rep; }
    __syncthreads();
    if (threadIdx.x == 0) {
        float A = sA[0] + sA[1] + sA[2] + sA[3];
        float R = sR[0] + sR[1] + sR[2] + sR[3];
        int bin = (int)((blockIdx.y * gridDim.x + blockIdx.x) & (NBINS - 1));
        atomicAdd(&bins[2 * bin], (double)A);
        atomicAdd(&bins[2 * bin + 1], (double)R);
        __threadfence();
        unsigned int old = atomicAdd(doneB, 1u);
        isLast = (old == (unsigned int)(totalB - 1)) ? 1 : 0;
    }
    __syncthreads();
    if (isLast && threadIdx.x < 64) {
        double a = 0.0, r = 0.0;
        if (threadIdx.x < NBINS) {
            a = atomicAdd(&bins[2 * threadIdx.x], 0.0);      // coherent read
            r = atomicAdd(&bins[2 * threadIdx.x + 1], 0.0);
        }
        #pragma unroll
        for (int off = 8; off > 0; off >>= 1) {
            a += __shfl_down(a, off, 64);
            r += __shfl_down(r, off, 64);
        }
        if (threadIdx.x == 0) {
            out[0] = (float)(a / (double)(*nmask));
            out[1] = (float)(r / (double)N_HITS);
        }
    }
}

extern "C" void kernel_launch(void* const* d_in, const int* in_sizes, int n_in,
                              void* d_out, int out_size, void* d_ws, size_t ws_size,
                              hipStream_t stream) {
    const float* beta  = (const float*)d_in[0];
    const float* x     = (const float*)d_in[1];
    const int*   pid   = (const int*)d_in[2];
    const int*   recon = (const int*)d_in[3];
    const float* tp    = (const float*)d_in[4];
    float* out = (float*)d_out;

    char* ws = (char*)d_ws;
    unsigned long long* best  = (unsigned long long*)(ws);
    unsigned int*       doneA = (unsigned int*)(ws + 2400);
    unsigned int*       doneB = (unsigned int*)(ws + 2404);
    unsigned int*       nmask = (unsigned int*)(ws + 2408);
    double*             bins  = (double*)(ws + 2416);
    float4*             c     = (float4*)(ws + 2688);

    const int nblocksA = (N_HITS + 255) / 256;          // 391
    const int nblocksBx = (N_HITS + TILE - 1) / TILE;   // 98
    const int totalB = nblocksBx * NSPLIT;              // 1960 (<= 2048 co-resident)

    hipMemsetAsync(d_ws, 0, 2672, stream);

    kA_scan<<<nblocksA, 256, 0, stream>>>(beta, x, pid, recon, tp,
                                          best, nmask, doneA, c, nblocksA);
    kB_main<<<dim3(nblocksBx, NSPLIT), 256, 0, stream>>>(beta, x, pid, recon, tp,
                                                         c, nmask, bins, doneB,
                                                         out, totalB);
}

// Round 6
// 97.055 us; speedup vs baseline: 1.4213x; 1.4213x over previous
//
#include <hip/hip_runtime.h>
#include <math.h>

#define N_HITS 100000
#define P_PART 300
#define NSPLIT 20
#define PB (P_PART / NSPLIT)   // 15 centers per y-split
#define HPT 4                  // hits per thread
#define TILE (256 * HPT)       // 1024 hits per block-x
#define NBINS 512              // spread bin-pairs (16B each) -> 128 cachelines
#define KA_BLOCKS 80
#define Q_MIN 0.01f
#define R_THLD 10.0f
#define PT_THLD 0.9f

// ws layout (bytes):
//   [0,    2400): u64 best[300]                 (zeroed)  packed (beta_bits<<32)|~i
//   [2400, 2404): u32 doneA                     (zeroed)
//   [2408, 2412): u32 nmask                     (zeroed)
//   [2432, 10624): double bins[512][2]          (zeroed)
//   [10624,20224): float4 c[600]: c[2p]=x_a[p], c[2p+1]=(|x_a|^2, q_a, 0, 0)

__global__ __launch_bounds__(256) void kA_scan(
        const float* __restrict__ beta,
        const float* __restrict__ x,
        const int* __restrict__ pid,
        const int* __restrict__ recon,
        const float* __restrict__ tp,
        unsigned long long* __restrict__ best,
        unsigned int* __restrict__ nmask,
        unsigned int* __restrict__ doneA,
        float4* __restrict__ c) {
    __shared__ unsigned long long bloc[P_PART];
    __shared__ int sCnt[4];
    __shared__ int isLast;
    for (int s = threadIdx.x; s < P_PART; s += 256) bloc[s] = 0ULL;
    __syncthreads();

    int cnt = 0;
    for (int i = blockIdx.x * 256 + threadIdx.x; i < N_HITS; i += KA_BLOCKS * 256) {
        int p = pid[i];
        if (p > 0) {
            // q = atanh(b)^2 + c monotonic in b -> argmax q == argmax beta.
            // beta > 0 -> float bits order like values; ~i picks smallest i on ties
            // (jnp.argmax first-occurrence semantics).
            unsigned long long pack =
                ((unsigned long long)__float_as_uint(beta[i]) << 32) |
                (unsigned long long)(~(unsigned int)i);
            atomicMax(&bloc[p - 1], pack);   // LDS atomic: bank-parallel, cheap
        }
        cnt += (recon[i] > 0 && tp[i] > PT_THLD) ? 1 : 0;
    }
    __syncthreads();                          // all LDS atomics done

    // flush block-local table -> global (fire-and-forget, 300/block)
    for (int s = threadIdx.x; s < P_PART; s += 256) {
        unsigned long long v = bloc[s];
        if (v) atomicMax(&best[s], v);
    }
    // nmask: register count -> block reduce -> ONE global atomic per block
    #pragma unroll
    for (int off = 32; off > 0; off >>= 1) cnt += __shfl_down(cnt, off, 64);
    if ((threadIdx.x & 63) == 0) sCnt[threadIdx.x >> 6] = cnt;
    __threadfence();                          // order this thread's flush atomics
    __syncthreads();                          // drains vmcnt for the whole block
    if (threadIdx.x == 0) {
        atomicAdd(nmask, (unsigned int)(sCnt[0] + sCnt[1] + sCnt[2] + sCnt[3]));
        unsigned int old = atomicAdd(doneA, 1u);
        isLast = (old == (unsigned int)(KA_BLOCKS - 1)) ? 1 : 0;
    }
    __syncthreads();
    if (isLast) {                             // last block gathers centers
        for (int s = threadIdx.x; s < P_PART; s += 256) {
            unsigned long long b = atomicOr(&best[s], 0ULL);  // coherent read
            unsigned int idx = (b == 0ULL) ? 0u : ~(unsigned int)(b & 0xffffffffULL);
            float a = atanhf(beta[idx]);
            float4 xa = reinterpret_cast<const float4*>(x)[idx];
            float na = xa.x * xa.x + xa.y * xa.y + xa.z * xa.z + xa.w * xa.w;
            c[2 * s] = xa;
            c[2 * s + 1] = make_float4(na, a * a + Q_MIN, 0.f, 0.f);
        }
    }
}

__global__ __launch_bounds__(256, 8) void kB_main(
        const float* __restrict__ beta,
        const float* __restrict__ x,
        const int* __restrict__ pid,
        const int* __restrict__ recon,
        const float* __restrict__ tp,
        const float4* __restrict__ c,
        double* __restrict__ bins) {
    __shared__ float4 xa_s[PB];
    __shared__ float2 nq_s[PB];     // (|x_a|^2, q_a)
    int p0 = blockIdx.y * PB;
    if (threadIdx.x < PB) {
        float4 r1 = c[2 * (p0 + threadIdx.x) + 1];
        xa_s[threadIdx.x] = c[2 * (p0 + threadIdx.x)];
        nq_s[threadIdx.x] = make_float2(r1.x, r1.y);
    }
    __syncthreads();

    int base = blockIdx.x * TILE + threadIdx.x;
    float4 m2[HPT];                 // -2 * x_i
    float  sx[HPT];                 // |x_i|^2 + 1e-8
    float  q[HPT], aq[HPT], racc[HPT];
    int    pm1[HPT];
    #pragma unroll
    for (int h = 0; h < HPT; ++h) {
        int i = base + h * 256;
        bool valid = (i < N_HITS);
        int ii = valid ? i : 0;
        float4 xi = reinterpret_cast<const float4*>(x)[ii];
        m2[h] = make_float4(-2.f * xi.x, -2.f * xi.y, -2.f * xi.z, -2.f * xi.w);
        sx[h] = xi.x * xi.x + xi.y * xi.y + xi.z * xi.z + xi.w * xi.w + 1e-8f;
        float a = atanhf(beta[ii]);
        q[h] = valid ? (a * a + Q_MIN) : 0.f;    // q=0 nullifies OOB lanes
        pm1[h] = valid ? (pid[ii] - 1) : -1;
        aq[h] = (valid && recon[ii] > 0 && tp[ii] > PT_THLD) ? q[h] : 0.f;
        racc[h] = 0.f;
    }

    #pragma unroll 5
    for (int p = 0; p < PB; ++p) {
        float4 xa = xa_s[p];        // uniform -> LDS broadcast, 0 conflicts
        float2 nq = nq_s[p];
        #pragma unroll
        for (int h = 0; h < HPT; ++h) {
            float n = sx[h] + nq.x;
            n = fmaf(m2[h].x, xa.x, n);
            n = fmaf(m2[h].y, xa.y, n);
            n = fmaf(m2[h].z, xa.z, n);
            n = fmaf(m2[h].w, xa.w, n);
            float s = __builtin_amdgcn_sqrtf(fmaxf(n, 0.f));   // raw v_sqrt_f32
            racc[h] = fmaf(fmaxf(R_THLD - s, 0.f), nq.y, racc[h]);
        }
    }

    float att = 0.f, rep = 0.f;
    #pragma unroll
    for (int h = 0; h < HPT; ++h) {
        int lp = pm1[h] - p0;
        if (lp >= 0 && lp < PB) {   // this split owns the own-pid term
            float4 xa = xa_s[lp];
            float2 nq = nq_s[lp];
            // IDENTICAL op sequence as the loop -> exact cancellation
            float n = sx[h] + nq.x;
            n = fmaf(m2[h].x, xa.x, n);
            n = fmaf(m2[h].y, xa.y, n);
            n = fmaf(m2[h].z, xa.z, n);
            n = fmaf(m2[h].w, xa.w, n);
            float s = __builtin_amdgcn_sqrtf(fmaxf(n, 0.f));
            racc[h] -= fmaxf(R_THLD - s, 0.f) * nq.y;
            att += aq[h] * (n - 1e-8f) * nq.y;   // attractive: nsq without eps
        }
        rep += q[h] * racc[h];
    }

    // wave-64 shuffle reduce, then block reduce, then spread-bin atomics
    #pragma unroll
    for (int off = 32; off > 0; off >>= 1) {
        att += __shfl_down(att, off, 64);
        rep += __shfl_down(rep, off, 64);
    }
    __shared__ float sA[4], sR[4];
    int wid = threadIdx.x >> 6;
    if ((threadIdx.x & 63) == 0) { sA[wid] = att; sR[wid] = rep; }
    __syncthreads();
    if (threadIdx.x == 0) {
        float A = sA[0] + sA[1] + sA[2] + sA[3];
        float R = sR[0] + sR[1] + sR[2] + sR[3];
        int bin = (int)((blockIdx.y * gridDim.x + blockIdx.x) & (NBINS - 1));
        atomicAdd(&bins[2 * bin], (double)A);        // fire-and-forget f64
        atomicAdd(&bins[2 * bin + 1], (double)R);
    }
}

__global__ __launch_bounds__(256) void kC_fin(
        const double* __restrict__ bins,
        const unsigned int* __restrict__ nmask,
        float* __restrict__ out) {
    double a = 0.0, r = 0.0;
    for (int t = threadIdx.x; t < NBINS; t += 256) {
        a += bins[2 * t];
        r += bins[2 * t + 1];
    }
    #pragma unroll
    for (int off = 32; off > 0; off >>= 1) {
        a += __shfl_down(a, off, 64);
        r += __shfl_down(r, off, 64);
    }
    __shared__ double dA[4], dR[4];
    int wid = threadIdx.x >> 6;
    if ((threadIdx.x & 63) == 0) { dA[wid] = a; dR[wid] = r; }
    __syncthreads();
    if (threadIdx.x == 0) {
        a = dA[0] + dA[1] + dA[2] + dA[3];
        r = dR[0] + dR[1] + dR[2] + dR[3];
        out[0] = (float)(a / (double)(*nmask));
        out[1] = (float)(r / (double)N_HITS);
    }
}

extern "C" void kernel_launch(void* const* d_in, const int* in_sizes, int n_in,
                              void* d_out, int out_size, void* d_ws, size_t ws_size,
                              hipStream_t stream) {
    const float* beta  = (const float*)d_in[0];
    const float* x     = (const float*)d_in[1];
    const int*   pid   = (const int*)d_in[2];
    const int*   recon = (const int*)d_in[3];
    const float* tp    = (const float*)d_in[4];
    float* out = (float*)d_out;

    char* ws = (char*)d_ws;
    unsigned long long* best  = (unsigned long long*)(ws);
    unsigned int*       doneA = (unsigned int*)(ws + 2400);
    unsigned int*       nmask = (unsigned int*)(ws + 2408);
    double*             bins  = (double*)(ws + 2432);
    float4*             c     = (float4*)(ws + 10624);

    const int nblocksBx = (N_HITS + TILE - 1) / TILE;   // 98

    hipMemsetAsync(d_ws, 0, 10624, stream);

    kA_scan<<<KA_BLOCKS, 256, 0, stream>>>(beta, x, pid, recon, tp,
                                           best, nmask, doneA, c);
    kB_main<<<dim3(nblocksBx, NSPLIT), 256, 0, stream>>>(beta, x, pid, recon, tp,
                                                         c, bins);
    kC_fin<<<1, 256, 0, stream>>>(bins, nmask, out);
}